// Round 5
// baseline (566.112 us; speedup 1.0000x reference)
//
#include <hip/hip_runtime.h>
#include <hip/hip_bf16.h>

// ---------------------------------------------------------------------------
// DiT block, bf16 MFMA, round 5.
// Changes vs r4: split-K=4 W2 GEMM (atomicAdd fp32 epilogue) to fix grid
// starvation (Occupancy 15%); attention P written as b64 (kv-permutation
// pi(kv)=(kv&15)*4+(kv>>4) folded into V^T global layout).
// ---------------------------------------------------------------------------

#define D_EMB 768
#define N_HEADS 12
#define HEAD 64
#define B_SZ 8
#define T_IMG 1024
#define T_CTX 256
#define FF_DIM 3072
#define ROWS_IMG (B_SZ * T_IMG)      // 8192
#define ROWS_CTX (B_SZ * T_CTX)     // 2048
#define BIGCOL (1 << 28)

typedef __bf16 bf16x8 __attribute__((ext_vector_type(8)));
typedef __bf16 bf16x4 __attribute__((ext_vector_type(4)));
typedef float f32x4 __attribute__((ext_vector_type(4)));

__device__ __forceinline__ void gld16(const void* g, void* l) {
    __builtin_amdgcn_global_load_lds(
        (const __attribute__((address_space(1))) unsigned int*)g,
        (__attribute__((address_space(3))) unsigned int*)l, 16, 0, 0);
}

// ---------------- copy (x init) ----------------
__global__ __launch_bounds__(256) void copy4_kernel(const float4* __restrict__ src,
                                                    float4* __restrict__ dst) {
    int i = blockIdx.x * 256 + threadIdx.x;
    dst[i] = src[i];
}

// ---------------- fp32 -> bf16 convert (ctx) ----------------
__global__ __launch_bounds__(256) void cvt_bf16_kernel(const float* __restrict__ src,
                                                       __bf16* __restrict__ dst, int n4) {
    int i = blockIdx.x * 256 + threadIdx.x;
    if (i >= n4) return;
    float4 v = ((const float4*)src)[i];
    __bf16* d = dst + i * 4;
    d[0] = (__bf16)v.x; d[1] = (__bf16)v.y; d[2] = (__bf16)v.z; d[3] = (__bf16)v.w;
}

// ---------------- tiled transpose fp32 -> bf16: dst[c][r] = src[r][c] -------
__global__ __launch_bounds__(256) void transpose_cvt_kernel(
    const float* __restrict__ src, __bf16* __restrict__ dst,
    int src_rows, int src_cols) {
    __shared__ float tile[64][65];
    int tid = threadIdx.x;
    int r0 = blockIdx.y * 64, c0 = blockIdx.x * 64;
    int lr = tid >> 4, lc = (tid & 15) * 4;
#pragma unroll
    for (int i = 0; i < 4; i++) {
        float4 v = *(const float4*)&src[(size_t)(r0 + i * 16 + lr) * src_cols + c0 + lc];
        tile[i * 16 + lr][lc] = v.x; tile[i * 16 + lr][lc + 1] = v.y;
        tile[i * 16 + lr][lc + 2] = v.z; tile[i * 16 + lr][lc + 3] = v.w;
    }
    __syncthreads();
#pragma unroll
    for (int i = 0; i < 4; i++) {
        int cc = i * 16 + lr;
        int rr = (tid & 15) * 4;
        bf16x4 o;
#pragma unroll
        for (int j = 0; j < 4; j++) o[j] = (__bf16)tile[rr + j][cc];
        *(bf16x4*)&dst[(size_t)(c0 + cc) * src_rows + r0 + rr] = o;
    }
}

// ---------------- repack per-head qkv weights -> transposed bf16 [2304][768]
__global__ __launch_bounds__(256) void repack_qkv_t_kernel(
    const float* __restrict__ Wq, const float* __restrict__ Wk, const float* __restrict__ Wv,
    const float* __restrict__ bq, const float* __restrict__ bk, const float* __restrict__ bv,
    __bf16* __restrict__ Wt, float* __restrict__ bp) {
    __shared__ float tile[64][65];
    int tid = threadIdx.x;
    int which = blockIdx.y / 12, h = blockIdx.y - which * 12;
    int d0 = blockIdx.x * 64;
    const float* W = (which == 0) ? Wq : ((which == 1) ? Wk : Wv);
    const float* src = W + ((size_t)h * D_EMB + d0) * HEAD;
    int lr = tid >> 4, lc = (tid & 15) * 4;
#pragma unroll
    for (int i = 0; i < 4; i++) {
        float4 v = *(const float4*)&src[(size_t)(i * 16 + lr) * HEAD + lc];
        tile[i * 16 + lr][lc] = v.x; tile[i * 16 + lr][lc + 1] = v.y;
        tile[i * 16 + lr][lc + 2] = v.z; tile[i * 16 + lr][lc + 3] = v.w;
    }
    __syncthreads();
#pragma unroll
    for (int i = 0; i < 4; i++) {
        int e = i * 16 + lr;
        int dd = (tid & 15) * 4;
        bf16x4 o;
#pragma unroll
        for (int j = 0; j < 4; j++) o[j] = (__bf16)tile[dd + j][e];
        *(bf16x4*)&Wt[(size_t)(which * 768 + h * 64 + e) * D_EMB + d0 + dd] = o;
    }
    if (blockIdx.x == 0 && tid < 64) {
        const float* bb = (which == 0) ? bq : ((which == 1) ? bk : bv);
        bp[which * 768 + h * 64 + tid] = bb[h * 64 + tid];
    }
}

// ---------------- layernorm over 768, bf16 output ----------------
__global__ __launch_bounds__(256) void ln_kernel(const float* __restrict__ x,
                                                 const float* __restrict__ lw,
                                                 const float* __restrict__ lb,
                                                 __bf16* __restrict__ y) {
    int row = blockIdx.x;
    int tid = threadIdx.x;
    const float* xr = x + (size_t)row * D_EMB;
    float a0 = xr[tid], a1 = xr[tid + 256], a2 = xr[tid + 512];
    float s = a0 + a1 + a2;
    float ss = a0 * a0 + a1 * a1 + a2 * a2;
#pragma unroll
    for (int off = 32; off > 0; off >>= 1) {
        s += __shfl_down(s, off, 64);
        ss += __shfl_down(ss, off, 64);
    }
    __shared__ float red[8];
    __shared__ float stats[2];
    int wv = tid >> 6, lane = tid & 63;
    if (lane == 0) { red[wv] = s; red[4 + wv] = ss; }
    __syncthreads();
    if (tid == 0) {
        float S = red[0] + red[1] + red[2] + red[3];
        float SS = red[4] + red[5] + red[6] + red[7];
        float mu = S * (1.0f / D_EMB);
        float var = SS * (1.0f / D_EMB) - mu * mu;
        stats[0] = mu;
        stats[1] = rsqrtf(var + 1e-5f);
    }
    __syncthreads();
    float mu = stats[0], rs = stats[1];
    __bf16* yr = y + (size_t)row * D_EMB;
    yr[tid]       = (__bf16)((a0 - mu) * rs * lw[tid]       + lb[tid]);
    yr[tid + 256] = (__bf16)((a1 - mu) * rs * lw[tid + 256] + lb[tid + 256]);
    yr[tid + 512] = (__bf16)((a2 - mu) * rs * lw[tid + 512] + lb[tid + 512]);
}

// ---------------- bf16 MFMA GEMM (B^T layout), optional split-K -------------
// Kc = K per z-chunk (K total = Kc * gridDim.z). Epilogue routing:
//   Cf != null          : fp32 atomicAdd into Cf (bias only on z==0)
//   col in [vcol0, N)   : bf16 V^T, token pi-permuted + granule-XOR swizzled
//   col in [kcol0,kcol1): bf16 K, within-head granule-XOR swizzle
//   else                : plain bf16
__global__ __launch_bounds__(256) void mfma_gemm_bt(
    const __bf16* __restrict__ A, int lda,
    const __bf16* __restrict__ Bt, int ldb,
    const float* __restrict__ bias,
    float* __restrict__ Cf, __bf16* __restrict__ Cb, int ldc,
    int Kc, int act, int qlimit,
    __bf16* __restrict__ VTout, int vtok, int vcol0, int kcol0, int kcol1) {
    __shared__ __bf16 As[128 * 32];
    __shared__ __bf16 Bs[128 * 32];
    int tid = threadIdx.x;
    int bx = blockIdx.x, by = blockIdx.y, kz = blockIdx.z;
    int w = tid >> 6, lane = tid & 63;
    int c = lane & 15, quad = lane >> 4;
    int wm = (w >> 1) * 64, wn = (w & 1) * 64;

    f32x4 acc[4][4];
#pragma unroll
    for (int i = 0; i < 4; i++)
#pragma unroll
        for (int j = 0; j < 4; j++) acc[i][j] = (f32x4){0.f, 0.f, 0.f, 0.f};

    int srow = tid >> 2;
    int scol = (tid & 3) * 8;
    const __bf16* Ag = A + (size_t)(by * 128 + srow) * lda + (size_t)kz * Kc + scol;
    const __bf16* Bg = Bt + (size_t)(bx * 128 + srow) * ldb + (size_t)kz * Kc + scol;
    char* AsB = (char*)As + w * 1024;
    char* BsB = (char*)Bs + w * 1024;

    for (int k0 = 0; k0 < Kc; k0 += 32) {
        gld16(Ag + k0, AsB);
        gld16(Ag + (size_t)64 * lda + k0, AsB + 4096);
        gld16(Bg + k0, BsB);
        gld16(Bg + (size_t)64 * ldb + k0, BsB + 4096);
        __syncthreads();
        bf16x8 af[4], bfr[4];
#pragma unroll
        for (int mi = 0; mi < 4; mi++)
            af[mi] = *(const bf16x8*)&As[(wm + mi * 16 + c) * 32 + quad * 8];
#pragma unroll
        for (int ni = 0; ni < 4; ni++)
            bfr[ni] = *(const bf16x8*)&Bs[(wn + ni * 16 + c) * 32 + quad * 8];
#pragma unroll
        for (int mi = 0; mi < 4; mi++)
#pragma unroll
            for (int ni = 0; ni < 4; ni++)
                acc[mi][ni] = __builtin_amdgcn_mfma_f32_16x16x32_bf16(
                    af[mi], bfr[ni], acc[mi][ni], 0, 0, 0);
        __syncthreads();
    }

#pragma unroll
    for (int mi = 0; mi < 4; mi++) {
#pragma unroll
        for (int ni = 0; ni < 4; ni++) {
            int row = by * 128 + wm + mi * 16 + quad * 4;
            int col = bx * 128 + wn + ni * 16 + c;
            float bv = (bias && kz == 0) ? bias[col] : 0.0f;
            float qs = (col < qlimit) ? 0.125f : 1.0f;
            float v[4];
#pragma unroll
            for (int r = 0; r < 4; r++) {
                float t = (acc[mi][ni][r] + bv) * qs;
                if (act == 1) t = t / (1.0f + __expf(-t));
                v[r] = t;
            }
            if (Cf) {
#pragma unroll
                for (int r = 0; r < 4; r++)
                    atomicAdd(&Cf[(size_t)(row + r) * ldc + col], v[r]);
            } else if (VTout && col >= vcol0) {
                int hc = col - vcol0;
                int hh = hc >> 6, e = hc & 63;
#pragma unroll
                for (int r = 0; r < 4; r++) {
                    int tok = row + r;
                    int u = tok & 63;
                    int sp = ((u & 15) << 2) | (u >> 4);          // pi(u)
                    int sl = ((((sp >> 3) & 7) ^ (e & 7)) << 3) | (sp & 7);
                    VTout[(size_t)(hh * 64 + e) * vtok + (tok & ~63) + sl] = (__bf16)v[r];
                }
            } else if (col >= kcol0 && col < kcol1) {
                int hc = col - kcol0;
                int hh = hc >> 6, e = hc & 63;
#pragma unroll
                for (int r = 0; r < 4; r++) {
                    int tok = row + r;
                    int es = (((e >> 3) ^ (tok & 7)) << 3) | (e & 7);
                    Cb[(size_t)tok * ldc + kcol0 + hh * 64 + es] = (__bf16)v[r];
                }
            } else {
#pragma unroll
                for (int r = 0; r < 4; r++)
                    Cb[(size_t)(row + r) * ldc + col] = (__bf16)v[r];
            }
        }
    }
}

// ---------------- flash MFMA attention, 128 q/block, swizzled K/V -----------
// Q [8192][qld] bf16 (pre-scaled), K' [tok][kld] swizzled per-head at h*64,
// VTg [12*64][vtok] per-head V^T, pi-permuted + granule-swizzled tokens.
// X [8192][768] fp32 += softmax(QK^T) V. grid 768 = (b,h)*8 qtiles, block 128.
__global__ __launch_bounds__(128, 2) void mfma_attn(
    const __bf16* __restrict__ Q, int qld,
    const __bf16* __restrict__ Kp, int kld,
    const __bf16* __restrict__ VTg, int vtok,
    int kv_tokens, float* __restrict__ X) {
    __shared__ __bf16 Kt[64 * 64];     // [s][d] swizzled granules
    __shared__ __bf16 VT[80 * 64];     // [e][s'] swizzled; rows 64..79 ones/zeros
    __shared__ __bf16 Ps[128 * 76];    // [q][s'] stride 76; also Q staging (stride 64)
    int tid = threadIdx.x;
    int qt = blockIdx.x & 7;
    int bh = blockIdx.x >> 3;
    int b = bh / N_HEADS, h = bh - b * N_HEADS;
    int w = tid >> 6, lane = tid & 63, c = lane & 15, quad = lane >> 4;
    int q0 = qt * 128;

    // ones/zeros tail rows of VT (swizzle-invariant: constant per row)
    for (int i = tid; i < 16 * 64; i += 128)
        VT[64 * 64 + i] = (i < 64) ? (__bf16)1.0f : (__bf16)0.0f;

    // stage Q (128x64) into Ps area, stride 64
    {
        const __bf16* Qg = Q + (size_t)(b * T_IMG + q0 + (tid >> 3)) * qld
                           + h * HEAD + (tid & 7) * 8;
        char* QsB = (char*)Ps + w * 1024;
#pragma unroll
        for (int j = 0; j < 8; j++)
            gld16(Qg + (size_t)j * 16 * qld, QsB + j * 2048);
    }
    __syncthreads();
    bf16x8 qa[4][2];
#pragma unroll
    for (int st = 0; st < 4; st++)
#pragma unroll
        for (int ch = 0; ch < 2; ch++)
            qa[st][ch] = *(const bf16x8*)&Ps[(w * 64 + st * 16 + c) * 64 + ch * 32 + quad * 8];
    __syncthreads();

    f32x4 o[4][5];
#pragma unroll
    for (int st = 0; st < 4; st++)
#pragma unroll
        for (int ut = 0; ut < 5; ut++) o[st][ut] = (f32x4){0.f, 0.f, 0.f, 0.f};

    char* KtB = (char*)Kt + w * 1024;
    char* VtB = (char*)VT + w * 1024;
    int ntiles = kv_tokens >> 6;
    for (int t = 0; t < ntiles; t++) {
        const __bf16* Kg = Kp + (size_t)(b * kv_tokens + t * 64 + (tid >> 3)) * kld
                           + h * HEAD + (tid & 7) * 8;
        const __bf16* Vg = VTg + (size_t)(h * HEAD + (tid >> 3)) * vtok
                           + b * kv_tokens + t * 64 + (tid & 7) * 8;
#pragma unroll
        for (int j = 0; j < 4; j++) {
            gld16(Kg + (size_t)j * 16 * kld, KtB + j * 2048);
            gld16(Vg + (size_t)j * 16 * vtok, VtB + j * 2048);
        }
        __syncthreads();   // (1) K/V tiles visible

        // ---- S = Q K^T, per strip; K frags shared across strips
        bf16x8 kb[4][2];
#pragma unroll
        for (int nt = 0; nt < 4; nt++)
#pragma unroll
            for (int ch = 0; ch < 2; ch++)
                kb[nt][ch] = *(const bf16x8*)&Kt[(nt * 16 + c) * 64
                                + (((ch * 4 + quad) ^ (c & 7)) << 3)];
#pragma unroll
        for (int st = 0; st < 4; st++) {
            f32x4 s[4];
#pragma unroll
            for (int nt = 0; nt < 4; nt++) {
                s[nt] = (f32x4){0.f, 0.f, 0.f, 0.f};
                s[nt] = __builtin_amdgcn_mfma_f32_16x16x32_bf16(qa[st][0], kb[nt][0], s[nt], 0, 0, 0);
                s[nt] = __builtin_amdgcn_mfma_f32_16x16x32_bf16(qa[st][1], kb[nt][1], s[nt], 0, 0, 0);
            }
            // P write: column s' = c*4 + nt (pi-permuted kv) -> b64 per r
#pragma unroll
            for (int r = 0; r < 4; r++) {
                bf16x4 pk;
#pragma unroll
                for (int nt = 0; nt < 4; nt++) pk[nt] = (__bf16)__expf(s[nt][r]);
                *(bf16x4*)&Ps[(size_t)(w * 64 + st * 16 + quad * 4 + r) * 76 + c * 4] = pk;
            }
        }
        __syncthreads();   // (2) P visible

        // ---- O += P V ; V frags shared across strips; ut=4 = ones row (l)
        bf16x8 vb[5][2];
#pragma unroll
        for (int ut = 0; ut < 5; ut++)
#pragma unroll
            for (int ch = 0; ch < 2; ch++)
                vb[ut][ch] = *(const bf16x8*)&VT[(ut * 16 + c) * 64
                                + (((ch * 4 + quad) ^ (c & 7)) << 3)];
#pragma unroll
        for (int st = 0; st < 4; st++) {
            bf16x8 pa0 = *(const bf16x8*)&Ps[(w * 64 + st * 16 + c) * 76 + quad * 8];
            bf16x8 pa1 = *(const bf16x8*)&Ps[(w * 64 + st * 16 + c) * 76 + 32 + quad * 8];
#pragma unroll
            for (int ut = 0; ut < 5; ut++) {
                o[st][ut] = __builtin_amdgcn_mfma_f32_16x16x32_bf16(pa0, vb[ut][0], o[st][ut], 0, 0, 0);
                o[st][ut] = __builtin_amdgcn_mfma_f32_16x16x32_bf16(pa1, vb[ut][1], o[st][ut], 0, 0, 0);
            }
        }
        __syncthreads();   // (3) safe to restage K/V/P
    }

    // ---- epilogue: l = o[st][4] at c==0 lanes; X += O / l
#pragma unroll
    for (int st = 0; st < 4; st++) {
        float lr[4];
#pragma unroll
        for (int r = 0; r < 4; r++) lr[r] = __shfl(o[st][4][r], lane & 48, 64);
#pragma unroll
        for (int ut = 0; ut < 4; ut++) {
#pragma unroll
            for (int r = 0; r < 4; r++) {
                int row = b * T_IMG + q0 + w * 64 + st * 16 + quad * 4 + r;
                int col = h * HEAD + ut * 16 + c;
                X[(size_t)row * D_EMB + col] += o[st][ut][r] / lr[r];
            }
        }
    }
}

// ---------------------------------------------------------------------------
extern "C" void kernel_launch(void* const* d_in, const int* in_sizes, int n_in,
                              void* d_out, int out_size, void* d_ws, size_t ws_size,
                              hipStream_t stream) {
    const float* img  = (const float*)d_in[0];
    const float* ctx  = (const float*)d_in[1];
    const float* ln1w = (const float*)d_in[2];  const float* ln1b = (const float*)d_in[3];
    const float* sWq  = (const float*)d_in[4];  const float* sbq  = (const float*)d_in[5];
    const float* sWk  = (const float*)d_in[6];  const float* sbk  = (const float*)d_in[7];
    const float* sWv  = (const float*)d_in[8];  const float* sbv  = (const float*)d_in[9];
    const float* ln2w = (const float*)d_in[10]; const float* ln2b = (const float*)d_in[11];
    const float* cWq  = (const float*)d_in[12]; const float* cbq  = (const float*)d_in[13];
    const float* cWk  = (const float*)d_in[14]; const float* cbk  = (const float*)d_in[15];
    const float* cWv  = (const float*)d_in[16]; const float* cbv  = (const float*)d_in[17];
    const float* ln3w = (const float*)d_in[18]; const float* ln3b = (const float*)d_in[19];
    const float* W1   = (const float*)d_in[20]; const float* b1   = (const float*)d_in[21];
    const float* W2   = (const float*)d_in[22]; const float* b2   = (const float*)d_in[23];

    float* X = (float*)d_out;

    // workspace layout (bytes)
    char* p = (char*)d_ws;
    __bf16* LNb  = (__bf16*)p; p += (size_t)ROWS_IMG * D_EMB * 2;       // 12.6 MB
    __bf16* BIG  = (__bf16*)p; p += (size_t)ROWS_IMG * FF_DIM * 2;      // 50.3 MB
    __bf16* ctxb = (__bf16*)p; p += (size_t)ROWS_CTX * D_EMB * 2;       // 3.1 MB
    __bf16* Wt   = (__bf16*)p; p += (size_t)2304 * 768 * 2;             // 3.5 MB
    __bf16* cWt  = (__bf16*)p; p += (size_t)2304 * 768 * 2;             // 3.5 MB
    __bf16* W1t  = (__bf16*)p; p += (size_t)FF_DIM * 768 * 2;           // 4.7 MB
    __bf16* W2t  = (__bf16*)p; p += (size_t)768 * FF_DIM * 2;           // 4.7 MB
    __bf16* VTg  = (__bf16*)p; p += (size_t)12 * 64 * ROWS_IMG * 2;     // 12.6 MB
    __bf16* VTc  = (__bf16*)p; p += (size_t)12 * 64 * ROWS_CTX * 2;     // 3.1 MB
    float*  bp   = (float*)p;  p += 2304 * 4;
    float*  cbp  = (float*)p;  p += 2304 * 4;
    // stage aliases in BIG:
    __bf16* QKVb = BIG;                           // [8192][2304] (V part unused)
    __bf16* Qc   = BIG;                           // [8192][768]
    __bf16* KVc  = BIG + (size_t)ROWS_IMG * 768;  // [2048][1536] (V part unused)
    __bf16* FFh  = BIG;                           // [8192][3072]

    // ---- x = img; weight preprocessing ----
    copy4_kernel<<<ROWS_IMG * D_EMB / 4 / 256, 256, 0, stream>>>(
        (const float4*)img, (float4*)X);
    cvt_bf16_kernel<<<(ROWS_CTX * D_EMB / 4 + 255) / 256, 256, 0, stream>>>(
        ctx, ctxb, ROWS_CTX * D_EMB / 4);
    repack_qkv_t_kernel<<<dim3(12, 36), 256, 0, stream>>>(
        sWq, sWk, sWv, sbq, sbk, sbv, Wt, bp);
    repack_qkv_t_kernel<<<dim3(12, 36), 256, 0, stream>>>(
        cWq, cWk, cWv, cbq, cbk, cbv, cWt, cbp);
    transpose_cvt_kernel<<<dim3(FF_DIM / 64, 768 / 64), 256, 0, stream>>>(
        W1, W1t, 768, FF_DIM);
    transpose_cvt_kernel<<<dim3(768 / 64, FF_DIM / 64), 256, 0, stream>>>(
        W2, W2t, FF_DIM, 768);

    // ---- stage 1: self attention ----
    ln_kernel<<<ROWS_IMG, 256, 0, stream>>>(X, ln1w, ln1b, LNb);
    mfma_gemm_bt<<<dim3(2304 / 128, ROWS_IMG / 128), 256, 0, stream>>>(
        LNb, D_EMB, Wt, D_EMB, bp, nullptr, QKVb, 2304, D_EMB, 0, 768,
        VTg, ROWS_IMG, 1536, 768, 1536);
    mfma_attn<<<96 * 8, 128, 0, stream>>>(
        QKVb, 2304, QKVb + 768, 2304, VTg, ROWS_IMG, T_IMG, X);

    // ---- stage 2: cross attention ----
    ln_kernel<<<ROWS_IMG, 256, 0, stream>>>(X, ln2w, ln2b, LNb);
    mfma_gemm_bt<<<dim3(768 / 128, ROWS_IMG / 128), 256, 0, stream>>>(
        LNb, D_EMB, cWt, D_EMB, cbp, nullptr, Qc, 768, D_EMB, 0, 768,
        nullptr, 0, BIGCOL, BIGCOL, BIGCOL);
    mfma_gemm_bt<<<dim3(1536 / 128, ROWS_CTX / 128), 256, 0, stream>>>(
        ctxb, D_EMB, cWt + (size_t)768 * 768, D_EMB, cbp + 768,
        nullptr, KVc, 1536, D_EMB, 0, 0,
        VTc, ROWS_CTX, 768, 0, 768);
    mfma_attn<<<96 * 8, 128, 0, stream>>>(
        Qc, 768, KVc, 1536, VTc, ROWS_CTX, T_CTX, X);

    // ---- stage 3: MLP ----
    ln_kernel<<<ROWS_IMG, 256, 0, stream>>>(X, ln3w, ln3b, LNb);
    mfma_gemm_bt<<<dim3(FF_DIM / 128, ROWS_IMG / 128), 256, 0, stream>>>(
        LNb, D_EMB, W1t, D_EMB, b1, nullptr, FFh, FF_DIM, D_EMB, 1, 0,
        nullptr, 0, BIGCOL, BIGCOL, BIGCOL);
    // W2: split-K=4 (K=3072 -> 4x768), fp32 atomicAdd into X
    mfma_gemm_bt<<<dim3(768 / 128, ROWS_IMG / 128, 4), 256, 0, stream>>>(
        FFh, FF_DIM, W2t, FF_DIM, b2, X, nullptr, D_EMB, 768, 0, 0,
        nullptr, 0, BIGCOL, BIGCOL, BIGCOL);
}

// Round 6
// 518.192 us; speedup vs baseline: 1.0925x; 1.0925x over previous
//
#include <hip/hip_runtime.h>
#include <hip/hip_bf16.h>

// ---------------------------------------------------------------------------
// DiT block, bf16 MFMA, round 6.
// vs r5: W2 split-K=2 with NON-atomic bf16 partials (overlaid on LNb+VTg,
// both dead at MLP time) + vectorized reduce kernel (X += P0+P1+b2).
// Atomic fp32 epilogue removed (r5's 4x WRITE_SIZE regression).
// ---------------------------------------------------------------------------

#define D_EMB 768
#define N_HEADS 12
#define HEAD 64
#define B_SZ 8
#define T_IMG 1024
#define T_CTX 256
#define FF_DIM 3072
#define ROWS_IMG (B_SZ * T_IMG)      // 8192
#define ROWS_CTX (B_SZ * T_CTX)     // 2048
#define BIGCOL (1 << 28)
#define PART_STRIDE (ROWS_IMG * D_EMB)   // 6291456 elems, split-K partial stride

typedef __bf16 bf16x8 __attribute__((ext_vector_type(8)));
typedef __bf16 bf16x4 __attribute__((ext_vector_type(4)));
typedef float f32x4 __attribute__((ext_vector_type(4)));

__device__ __forceinline__ void gld16(const void* g, void* l) {
    __builtin_amdgcn_global_load_lds(
        (const __attribute__((address_space(1))) unsigned int*)g,
        (__attribute__((address_space(3))) unsigned int*)l, 16, 0, 0);
}

// ---------------- copy (x init) ----------------
__global__ __launch_bounds__(256) void copy4_kernel(const float4* __restrict__ src,
                                                    float4* __restrict__ dst) {
    int i = blockIdx.x * 256 + threadIdx.x;
    dst[i] = src[i];
}

// ---------------- fp32 -> bf16 convert (ctx) ----------------
__global__ __launch_bounds__(256) void cvt_bf16_kernel(const float* __restrict__ src,
                                                       __bf16* __restrict__ dst, int n4) {
    int i = blockIdx.x * 256 + threadIdx.x;
    if (i >= n4) return;
    float4 v = ((const float4*)src)[i];
    __bf16* d = dst + i * 4;
    d[0] = (__bf16)v.x; d[1] = (__bf16)v.y; d[2] = (__bf16)v.z; d[3] = (__bf16)v.w;
}

// ---------------- W2 split-K reduce: X += P0 + P1 + b2 ----------------
__global__ __launch_bounds__(256) void reduce_w2_kernel(
    const __bf16* __restrict__ P, const float* __restrict__ b2,
    float* __restrict__ X) {
    int i = blockIdx.x * 256 + threadIdx.x;   // over ROWS_IMG*D_EMB/4
    int base = i * 4;
    int col = base % D_EMB;
    bf16x4 p0 = *(const bf16x4*)&P[base];
    bf16x4 p1 = *(const bf16x4*)&P[PART_STRIDE + base];
    float4 x = *(float4*)&X[base];
    float4 bb = *(const float4*)&b2[col];
    x.x += (float)p0[0] + (float)p1[0] + bb.x;
    x.y += (float)p0[1] + (float)p1[1] + bb.y;
    x.z += (float)p0[2] + (float)p1[2] + bb.z;
    x.w += (float)p0[3] + (float)p1[3] + bb.w;
    *(float4*)&X[base] = x;
}

// ---------------- tiled transpose fp32 -> bf16: dst[c][r] = src[r][c] -------
__global__ __launch_bounds__(256) void transpose_cvt_kernel(
    const float* __restrict__ src, __bf16* __restrict__ dst,
    int src_rows, int src_cols) {
    __shared__ float tile[64][65];
    int tid = threadIdx.x;
    int r0 = blockIdx.y * 64, c0 = blockIdx.x * 64;
    int lr = tid >> 4, lc = (tid & 15) * 4;
#pragma unroll
    for (int i = 0; i < 4; i++) {
        float4 v = *(const float4*)&src[(size_t)(r0 + i * 16 + lr) * src_cols + c0 + lc];
        tile[i * 16 + lr][lc] = v.x; tile[i * 16 + lr][lc + 1] = v.y;
        tile[i * 16 + lr][lc + 2] = v.z; tile[i * 16 + lr][lc + 3] = v.w;
    }
    __syncthreads();
#pragma unroll
    for (int i = 0; i < 4; i++) {
        int cc = i * 16 + lr;
        int rr = (tid & 15) * 4;
        bf16x4 o;
#pragma unroll
        for (int j = 0; j < 4; j++) o[j] = (__bf16)tile[rr + j][cc];
        *(bf16x4*)&dst[(size_t)(c0 + cc) * src_rows + r0 + rr] = o;
    }
}

// ---------------- repack per-head qkv weights -> transposed bf16 [2304][768]
__global__ __launch_bounds__(256) void repack_qkv_t_kernel(
    const float* __restrict__ Wq, const float* __restrict__ Wk, const float* __restrict__ Wv,
    const float* __restrict__ bq, const float* __restrict__ bk, const float* __restrict__ bv,
    __bf16* __restrict__ Wt, float* __restrict__ bp) {
    __shared__ float tile[64][65];
    int tid = threadIdx.x;
    int which = blockIdx.y / 12, h = blockIdx.y - which * 12;
    int d0 = blockIdx.x * 64;
    const float* W = (which == 0) ? Wq : ((which == 1) ? Wk : Wv);
    const float* src = W + ((size_t)h * D_EMB + d0) * HEAD;
    int lr = tid >> 4, lc = (tid & 15) * 4;
#pragma unroll
    for (int i = 0; i < 4; i++) {
        float4 v = *(const float4*)&src[(size_t)(i * 16 + lr) * HEAD + lc];
        tile[i * 16 + lr][lc] = v.x; tile[i * 16 + lr][lc + 1] = v.y;
        tile[i * 16 + lr][lc + 2] = v.z; tile[i * 16 + lr][lc + 3] = v.w;
    }
    __syncthreads();
#pragma unroll
    for (int i = 0; i < 4; i++) {
        int e = i * 16 + lr;
        int dd = (tid & 15) * 4;
        bf16x4 o;
#pragma unroll
        for (int j = 0; j < 4; j++) o[j] = (__bf16)tile[dd + j][e];
        *(bf16x4*)&Wt[(size_t)(which * 768 + h * 64 + e) * D_EMB + d0 + dd] = o;
    }
    if (blockIdx.x == 0 && tid < 64) {
        const float* bb = (which == 0) ? bq : ((which == 1) ? bk : bv);
        bp[which * 768 + h * 64 + tid] = bb[h * 64 + tid];
    }
}

// ---------------- layernorm over 768, bf16 output ----------------
__global__ __launch_bounds__(256) void ln_kernel(const float* __restrict__ x,
                                                 const float* __restrict__ lw,
                                                 const float* __restrict__ lb,
                                                 __bf16* __restrict__ y) {
    int row = blockIdx.x;
    int tid = threadIdx.x;
    const float* xr = x + (size_t)row * D_EMB;
    float a0 = xr[tid], a1 = xr[tid + 256], a2 = xr[tid + 512];
    float s = a0 + a1 + a2;
    float ss = a0 * a0 + a1 * a1 + a2 * a2;
#pragma unroll
    for (int off = 32; off > 0; off >>= 1) {
        s += __shfl_down(s, off, 64);
        ss += __shfl_down(ss, off, 64);
    }
    __shared__ float red[8];
    __shared__ float stats[2];
    int wv = tid >> 6, lane = tid & 63;
    if (lane == 0) { red[wv] = s; red[4 + wv] = ss; }
    __syncthreads();
    if (tid == 0) {
        float S = red[0] + red[1] + red[2] + red[3];
        float SS = red[4] + red[5] + red[6] + red[7];
        float mu = S * (1.0f / D_EMB);
        float var = SS * (1.0f / D_EMB) - mu * mu;
        stats[0] = mu;
        stats[1] = rsqrtf(var + 1e-5f);
    }
    __syncthreads();
    float mu = stats[0], rs = stats[1];
    __bf16* yr = y + (size_t)row * D_EMB;
    yr[tid]       = (__bf16)((a0 - mu) * rs * lw[tid]       + lb[tid]);
    yr[tid + 256] = (__bf16)((a1 - mu) * rs * lw[tid + 256] + lb[tid + 256]);
    yr[tid + 512] = (__bf16)((a2 - mu) * rs * lw[tid + 512] + lb[tid + 512]);
}

// ---------------- bf16 MFMA GEMM (B^T layout), optional split-K -------------
// Kc = K per z-chunk. Epilogue routing (all bf16):
//   col in [vcol0, N)   : V^T, token pi-permuted + granule-XOR swizzled
//   col in [kcol0,kcol1): K, within-head granule-XOR swizzle
//   else                : plain store at Cb + kz*PART_STRIDE (split-K partials;
//                         kz==0 for all non-split launches)
__global__ __launch_bounds__(256) void mfma_gemm_bt(
    const __bf16* __restrict__ A, int lda,
    const __bf16* __restrict__ Bt, int ldb,
    const float* __restrict__ bias,
    __bf16* __restrict__ Cb, int ldc,
    int Kc, int act, int qlimit,
    __bf16* __restrict__ VTout, int vtok, int vcol0, int kcol0, int kcol1) {
    __shared__ __bf16 As[128 * 32];
    __shared__ __bf16 Bs[128 * 32];
    int tid = threadIdx.x;
    int bx = blockIdx.x, by = blockIdx.y, kz = blockIdx.z;
    int w = tid >> 6, lane = tid & 63;
    int c = lane & 15, quad = lane >> 4;
    int wm = (w >> 1) * 64, wn = (w & 1) * 64;

    f32x4 acc[4][4];
#pragma unroll
    for (int i = 0; i < 4; i++)
#pragma unroll
        for (int j = 0; j < 4; j++) acc[i][j] = (f32x4){0.f, 0.f, 0.f, 0.f};

    int srow = tid >> 2;
    int scol = (tid & 3) * 8;
    const __bf16* Ag = A + (size_t)(by * 128 + srow) * lda + (size_t)kz * Kc + scol;
    const __bf16* Bg = Bt + (size_t)(bx * 128 + srow) * ldb + (size_t)kz * Kc + scol;
    char* AsB = (char*)As + w * 1024;
    char* BsB = (char*)Bs + w * 1024;

    for (int k0 = 0; k0 < Kc; k0 += 32) {
        gld16(Ag + k0, AsB);
        gld16(Ag + (size_t)64 * lda + k0, AsB + 4096);
        gld16(Bg + k0, BsB);
        gld16(Bg + (size_t)64 * ldb + k0, BsB + 4096);
        __syncthreads();
        bf16x8 af[4], bfr[4];
#pragma unroll
        for (int mi = 0; mi < 4; mi++)
            af[mi] = *(const bf16x8*)&As[(wm + mi * 16 + c) * 32 + quad * 8];
#pragma unroll
        for (int ni = 0; ni < 4; ni++)
            bfr[ni] = *(const bf16x8*)&Bs[(wn + ni * 16 + c) * 32 + quad * 8];
#pragma unroll
        for (int mi = 0; mi < 4; mi++)
#pragma unroll
            for (int ni = 0; ni < 4; ni++)
                acc[mi][ni] = __builtin_amdgcn_mfma_f32_16x16x32_bf16(
                    af[mi], bfr[ni], acc[mi][ni], 0, 0, 0);
        __syncthreads();
    }

#pragma unroll
    for (int mi = 0; mi < 4; mi++) {
#pragma unroll
        for (int ni = 0; ni < 4; ni++) {
            int row = by * 128 + wm + mi * 16 + quad * 4;
            int col = bx * 128 + wn + ni * 16 + c;
            float bv = (bias && kz == 0) ? bias[col] : 0.0f;
            float qs = (col < qlimit) ? 0.125f : 1.0f;
            float v[4];
#pragma unroll
            for (int r = 0; r < 4; r++) {
                float t = (acc[mi][ni][r] + bv) * qs;
                if (act == 1) t = t / (1.0f + __expf(-t));
                v[r] = t;
            }
            if (VTout && col >= vcol0) {
                int hc = col - vcol0;
                int hh = hc >> 6, e = hc & 63;
#pragma unroll
                for (int r = 0; r < 4; r++) {
                    int tok = row + r;
                    int u = tok & 63;
                    int sp = ((u & 15) << 2) | (u >> 4);          // pi(u)
                    int sl = ((((sp >> 3) & 7) ^ (e & 7)) << 3) | (sp & 7);
                    VTout[(size_t)(hh * 64 + e) * vtok + (tok & ~63) + sl] = (__bf16)v[r];
                }
            } else if (col >= kcol0 && col < kcol1) {
                int hc = col - kcol0;
                int hh = hc >> 6, e = hc & 63;
#pragma unroll
                for (int r = 0; r < 4; r++) {
                    int tok = row + r;
                    int es = (((e >> 3) ^ (tok & 7)) << 3) | (e & 7);
                    Cb[(size_t)tok * ldc + kcol0 + hh * 64 + es] = (__bf16)v[r];
                }
            } else {
                __bf16* dst = Cb + (size_t)kz * PART_STRIDE;
#pragma unroll
                for (int r = 0; r < 4; r++)
                    dst[(size_t)(row + r) * ldc + col] = (__bf16)v[r];
            }
        }
    }
}

// ---------------- flash MFMA attention, 128 q/block, swizzled K/V -----------
// Q [8192][qld] bf16 (pre-scaled), K' [tok][kld] swizzled per-head at h*64,
// VTg [12*64][vtok] per-head V^T, pi-permuted + granule-swizzled tokens.
// X [8192][768] fp32 += softmax(QK^T) V. grid 768 = (b,h)*8 qtiles, block 128.
__global__ __launch_bounds__(128, 2) void mfma_attn(
    const __bf16* __restrict__ Q, int qld,
    const __bf16* __restrict__ Kp, int kld,
    const __bf16* __restrict__ VTg, int vtok,
    int kv_tokens, float* __restrict__ X) {
    __shared__ __bf16 Kt[64 * 64];     // [s][d] swizzled granules
    __shared__ __bf16 VT[80 * 64];     // [e][s'] swizzled; rows 64..79 ones/zeros
    __shared__ __bf16 Ps[128 * 76];    // [q][s'] stride 76; also Q staging (stride 64)
    int tid = threadIdx.x;
    int qt = blockIdx.x & 7;
    int bh = blockIdx.x >> 3;
    int b = bh / N_HEADS, h = bh - b * N_HEADS;
    int w = tid >> 6, lane = tid & 63, c = lane & 15, quad = lane >> 4;
    int q0 = qt * 128;

    // ones/zeros tail rows of VT (swizzle-invariant: constant per row)
    for (int i = tid; i < 16 * 64; i += 128)
        VT[64 * 64 + i] = (i < 64) ? (__bf16)1.0f : (__bf16)0.0f;

    // stage Q (128x64) into Ps area, stride 64
    {
        const __bf16* Qg = Q + (size_t)(b * T_IMG + q0 + (tid >> 3)) * qld
                           + h * HEAD + (tid & 7) * 8;
        char* QsB = (char*)Ps + w * 1024;
#pragma unroll
        for (int j = 0; j < 8; j++)
            gld16(Qg + (size_t)j * 16 * qld, QsB + j * 2048);
    }
    __syncthreads();
    bf16x8 qa[4][2];
#pragma unroll
    for (int st = 0; st < 4; st++)
#pragma unroll
        for (int ch = 0; ch < 2; ch++)
            qa[st][ch] = *(const bf16x8*)&Ps[(w * 64 + st * 16 + c) * 64 + ch * 32 + quad * 8];
    __syncthreads();

    f32x4 o[4][5];
#pragma unroll
    for (int st = 0; st < 4; st++)
#pragma unroll
        for (int ut = 0; ut < 5; ut++) o[st][ut] = (f32x4){0.f, 0.f, 0.f, 0.f};

    char* KtB = (char*)Kt + w * 1024;
    char* VtB = (char*)VT + w * 1024;
    int ntiles = kv_tokens >> 6;
    for (int t = 0; t < ntiles; t++) {
        const __bf16* Kg = Kp + (size_t)(b * kv_tokens + t * 64 + (tid >> 3)) * kld
                           + h * HEAD + (tid & 7) * 8;
        const __bf16* Vg = VTg + (size_t)(h * HEAD + (tid >> 3)) * vtok
                           + b * kv_tokens + t * 64 + (tid & 7) * 8;
#pragma unroll
        for (int j = 0; j < 4; j++) {
            gld16(Kg + (size_t)j * 16 * kld, KtB + j * 2048);
            gld16(Vg + (size_t)j * 16 * vtok, VtB + j * 2048);
        }
        __syncthreads();   // (1) K/V tiles visible

        // ---- S = Q K^T, per strip; K frags shared across strips
        bf16x8 kb[4][2];
#pragma unroll
        for (int nt = 0; nt < 4; nt++)
#pragma unroll
            for (int ch = 0; ch < 2; ch++)
                kb[nt][ch] = *(const bf16x8*)&Kt[(nt * 16 + c) * 64
                                + (((ch * 4 + quad) ^ (c & 7)) << 3)];
#pragma unroll
        for (int st = 0; st < 4; st++) {
            f32x4 s[4];
#pragma unroll
            for (int nt = 0; nt < 4; nt++) {
                s[nt] = (f32x4){0.f, 0.f, 0.f, 0.f};
                s[nt] = __builtin_amdgcn_mfma_f32_16x16x32_bf16(qa[st][0], kb[nt][0], s[nt], 0, 0, 0);
                s[nt] = __builtin_amdgcn_mfma_f32_16x16x32_bf16(qa[st][1], kb[nt][1], s[nt], 0, 0, 0);
            }
            // P write: column s' = c*4 + nt (pi-permuted kv) -> b64 per r
#pragma unroll
            for (int r = 0; r < 4; r++) {
                bf16x4 pk;
#pragma unroll
                for (int nt = 0; nt < 4; nt++) pk[nt] = (__bf16)__expf(s[nt][r]);
                *(bf16x4*)&Ps[(size_t)(w * 64 + st * 16 + quad * 4 + r) * 76 + c * 4] = pk;
            }
        }
        __syncthreads();   // (2) P visible

        // ---- O += P V ; V frags shared across strips; ut=4 = ones row (l)
        bf16x8 vb[5][2];
#pragma unroll
        for (int ut = 0; ut < 5; ut++)
#pragma unroll
            for (int ch = 0; ch < 2; ch++)
                vb[ut][ch] = *(const bf16x8*)&VT[(ut * 16 + c) * 64
                                + (((ch * 4 + quad) ^ (c & 7)) << 3)];
#pragma unroll
        for (int st = 0; st < 4; st++) {
            bf16x8 pa0 = *(const bf16x8*)&Ps[(w * 64 + st * 16 + c) * 76 + quad * 8];
            bf16x8 pa1 = *(const bf16x8*)&Ps[(w * 64 + st * 16 + c) * 76 + 32 + quad * 8];
#pragma unroll
            for (int ut = 0; ut < 5; ut++) {
                o[st][ut] = __builtin_amdgcn_mfma_f32_16x16x32_bf16(pa0, vb[ut][0], o[st][ut], 0, 0, 0);
                o[st][ut] = __builtin_amdgcn_mfma_f32_16x16x32_bf16(pa1, vb[ut][1], o[st][ut], 0, 0, 0);
            }
        }
        __syncthreads();   // (3) safe to restage K/V/P
    }

    // ---- epilogue: l = o[st][4] at c==0 lanes; X += O / l
#pragma unroll
    for (int st = 0; st < 4; st++) {
        float lr[4];
#pragma unroll
        for (int r = 0; r < 4; r++) lr[r] = __shfl(o[st][4][r], lane & 48, 64);
#pragma unroll
        for (int ut = 0; ut < 4; ut++) {
#pragma unroll
            for (int r = 0; r < 4; r++) {
                int row = b * T_IMG + q0 + w * 64 + st * 16 + quad * 4 + r;
                int col = h * HEAD + ut * 16 + c;
                X[(size_t)row * D_EMB + col] += o[st][ut][r] / lr[r];
            }
        }
    }
}

// ---------------------------------------------------------------------------
extern "C" void kernel_launch(void* const* d_in, const int* in_sizes, int n_in,
                              void* d_out, int out_size, void* d_ws, size_t ws_size,
                              hipStream_t stream) {
    const float* img  = (const float*)d_in[0];
    const float* ctx  = (const float*)d_in[1];
    const float* ln1w = (const float*)d_in[2];  const float* ln1b = (const float*)d_in[3];
    const float* sWq  = (const float*)d_in[4];  const float* sbq  = (const float*)d_in[5];
    const float* sWk  = (const float*)d_in[6];  const float* sbk  = (const float*)d_in[7];
    const float* sWv  = (const float*)d_in[8];  const float* sbv  = (const float*)d_in[9];
    const float* ln2w = (const float*)d_in[10]; const float* ln2b = (const float*)d_in[11];
    const float* cWq  = (const float*)d_in[12]; const float* cbq  = (const float*)d_in[13];
    const float* cWk  = (const float*)d_in[14]; const float* cbk  = (const float*)d_in[15];
    const float* cWv  = (const float*)d_in[16]; const float* cbv  = (const float*)d_in[17];
    const float* ln3w = (const float*)d_in[18]; const float* ln3b = (const float*)d_in[19];
    const float* W1   = (const float*)d_in[20]; const float* b1   = (const float*)d_in[21];
    const float* W2   = (const float*)d_in[22]; const float* b2   = (const float*)d_in[23];

    float* X = (float*)d_out;

    // workspace layout (bytes). LNb and VTg are adjacent: together they form
    // the 2x(8192x768) bf16 split-K partial buffer for the W2 GEMM (both are
    // dead by MLP time).
    char* p = (char*)d_ws;
    __bf16* LNb  = (__bf16*)p; p += (size_t)ROWS_IMG * D_EMB * 2;       // 12.6 MB
    __bf16* VTg  = (__bf16*)p; p += (size_t)12 * 64 * ROWS_IMG * 2;     // 12.6 MB
    __bf16* BIG  = (__bf16*)p; p += (size_t)ROWS_IMG * FF_DIM * 2;      // 50.3 MB
    __bf16* ctxb = (__bf16*)p; p += (size_t)ROWS_CTX * D_EMB * 2;       // 3.1 MB
    __bf16* Wt   = (__bf16*)p; p += (size_t)2304 * 768 * 2;             // 3.5 MB
    __bf16* cWt  = (__bf16*)p; p += (size_t)2304 * 768 * 2;             // 3.5 MB
    __bf16* W1t  = (__bf16*)p; p += (size_t)FF_DIM * 768 * 2;           // 4.7 MB
    __bf16* W2t  = (__bf16*)p; p += (size_t)768 * FF_DIM * 2;           // 4.7 MB
    __bf16* VTc  = (__bf16*)p; p += (size_t)12 * 64 * ROWS_CTX * 2;     // 3.1 MB
    float*  bp   = (float*)p;  p += 2304 * 4;
    float*  cbp  = (float*)p;  p += 2304 * 4;
    __bf16* Pk   = LNb;   // split-K partials: [2][8192][768] bf16 overlay
    // stage aliases in BIG:
    __bf16* QKVb = BIG;                           // [8192][2304] (V part unused)
    __bf16* Qc   = BIG;                           // [8192][768]
    __bf16* KVc  = BIG + (size_t)ROWS_IMG * 768;  // [2048][1536] (V part unused)
    __bf16* FFh  = BIG;                           // [8192][3072]

    // ---- x = img; weight preprocessing ----
    copy4_kernel<<<ROWS_IMG * D_EMB / 4 / 256, 256, 0, stream>>>(
        (const float4*)img, (float4*)X);
    cvt_bf16_kernel<<<(ROWS_CTX * D_EMB / 4 + 255) / 256, 256, 0, stream>>>(
        ctx, ctxb, ROWS_CTX * D_EMB / 4);
    repack_qkv_t_kernel<<<dim3(12, 36), 256, 0, stream>>>(
        sWq, sWk, sWv, sbq, sbk, sbv, Wt, bp);
    repack_qkv_t_kernel<<<dim3(12, 36), 256, 0, stream>>>(
        cWq, cWk, cWv, cbq, cbk, cbv, cWt, cbp);
    transpose_cvt_kernel<<<dim3(FF_DIM / 64, 768 / 64), 256, 0, stream>>>(
        W1, W1t, 768, FF_DIM);
    transpose_cvt_kernel<<<dim3(768 / 64, FF_DIM / 64), 256, 0, stream>>>(
        W2, W2t, FF_DIM, 768);

    // ---- stage 1: self attention ----
    ln_kernel<<<ROWS_IMG, 256, 0, stream>>>(X, ln1w, ln1b, LNb);
    mfma_gemm_bt<<<dim3(2304 / 128, ROWS_IMG / 128), 256, 0, stream>>>(
        LNb, D_EMB, Wt, D_EMB, bp, QKVb, 2304, D_EMB, 0, 768,
        VTg, ROWS_IMG, 1536, 768, 1536);
    mfma_attn<<<96 * 8, 128, 0, stream>>>(
        QKVb, 2304, QKVb + 768, 2304, VTg, ROWS_IMG, T_IMG, X);

    // ---- stage 2: cross attention ----
    ln_kernel<<<ROWS_IMG, 256, 0, stream>>>(X, ln2w, ln2b, LNb);
    mfma_gemm_bt<<<dim3(768 / 128, ROWS_IMG / 128), 256, 0, stream>>>(
        LNb, D_EMB, cWt, D_EMB, cbp, Qc, 768, D_EMB, 0, 768,
        nullptr, 0, BIGCOL, BIGCOL, BIGCOL);
    mfma_gemm_bt<<<dim3(1536 / 128, ROWS_CTX / 128), 256, 0, stream>>>(
        ctxb, D_EMB, cWt + (size_t)768 * 768, D_EMB, cbp + 768,
        KVc, 1536, D_EMB, 0, 0,
        VTc, ROWS_CTX, 768, 0, 768);
    mfma_attn<<<96 * 8, 128, 0, stream>>>(
        Qc, 768, KVc, 1536, VTc, ROWS_CTX, T_CTX, X);

    // ---- stage 3: MLP ----
    ln_kernel<<<ROWS_IMG, 256, 0, stream>>>(X, ln3w, ln3b, LNb);
    mfma_gemm_bt<<<dim3(FF_DIM / 128, ROWS_IMG / 128), 256, 0, stream>>>(
        LNb, D_EMB, W1t, D_EMB, b1, FFh, FF_DIM, D_EMB, 1, 0,
        nullptr, 0, BIGCOL, BIGCOL, BIGCOL);
    // W2: split-K=2 (Kc=1536), bf16 partials into Pk (= LNb/VTg overlay)
    mfma_gemm_bt<<<dim3(768 / 128, ROWS_IMG / 128, 2), 256, 0, stream>>>(
        FFh, FF_DIM, W2t, FF_DIM, nullptr, Pk, D_EMB, 1536, 0, 0,
        nullptr, 0, BIGCOL, BIGCOL, BIGCOL);
    reduce_w2_kernel<<<ROWS_IMG * D_EMB / 4 / 256, 256, 0, stream>>>(Pk, b2, X);
}

// Round 7
// 507.685 us; speedup vs baseline: 1.1151x; 1.0207x over previous
//
#include <hip/hip_runtime.h>
#include <hip/hip_bf16.h>

// ---------------------------------------------------------------------------
// DiT block, bf16 MFMA, round 7.
// vs r6: operand-swapped MFMA (acc holds C^T fragments -> lane owns 4
// consecutive COLUMNS): GEMM epilogues become bf16x4 vector stores; attention
// S computed swapped so P writes are bf16x4 with NO kv permutation; pi removed
// from V^T global layout (fixes r5/r6 V^T 16x sector write-amplification).
// ---------------------------------------------------------------------------

#define D_EMB 768
#define N_HEADS 12
#define HEAD 64
#define B_SZ 8
#define T_IMG 1024
#define T_CTX 256
#define FF_DIM 3072
#define ROWS_IMG (B_SZ * T_IMG)      // 8192
#define ROWS_CTX (B_SZ * T_CTX)     // 2048
#define BIGCOL (1 << 28)
#define PART_STRIDE (ROWS_IMG * D_EMB)   // split-K partial stride (elems)

typedef __bf16 bf16x8 __attribute__((ext_vector_type(8)));
typedef __bf16 bf16x4 __attribute__((ext_vector_type(4)));
typedef float f32x4 __attribute__((ext_vector_type(4)));

__device__ __forceinline__ void gld16(const void* g, void* l) {
    __builtin_amdgcn_global_load_lds(
        (const __attribute__((address_space(1))) unsigned int*)g,
        (__attribute__((address_space(3))) unsigned int*)l, 16, 0, 0);
}

// ---------------- copy (x init) ----------------
__global__ __launch_bounds__(256) void copy4_kernel(const float4* __restrict__ src,
                                                    float4* __restrict__ dst) {
    int i = blockIdx.x * 256 + threadIdx.x;
    dst[i] = src[i];
}

// ---------------- fp32 -> bf16 convert (ctx) ----------------
__global__ __launch_bounds__(256) void cvt_bf16_kernel(const float* __restrict__ src,
                                                       __bf16* __restrict__ dst, int n4) {
    int i = blockIdx.x * 256 + threadIdx.x;
    if (i >= n4) return;
    float4 v = ((const float4*)src)[i];
    __bf16* d = dst + i * 4;
    d[0] = (__bf16)v.x; d[1] = (__bf16)v.y; d[2] = (__bf16)v.z; d[3] = (__bf16)v.w;
}

// ---------------- W2 split-K reduce: X += P0 + P1 + b2 ----------------
__global__ __launch_bounds__(256) void reduce_w2_kernel(
    const __bf16* __restrict__ P, const float* __restrict__ b2,
    float* __restrict__ X) {
    int i = blockIdx.x * 256 + threadIdx.x;
    int base = i * 4;
    int col = base % D_EMB;
    bf16x4 p0 = *(const bf16x4*)&P[base];
    bf16x4 p1 = *(const bf16x4*)&P[PART_STRIDE + base];
    float4 x = *(float4*)&X[base];
    float4 bb = *(const float4*)&b2[col];
    x.x += (float)p0[0] + (float)p1[0] + bb.x;
    x.y += (float)p0[1] + (float)p1[1] + bb.y;
    x.z += (float)p0[2] + (float)p1[2] + bb.z;
    x.w += (float)p0[3] + (float)p1[3] + bb.w;
    *(float4*)&X[base] = x;
}

// ---------------- tiled transpose fp32 -> bf16: dst[c][r] = src[r][c] -------
__global__ __launch_bounds__(256) void transpose_cvt_kernel(
    const float* __restrict__ src, __bf16* __restrict__ dst,
    int src_rows, int src_cols) {
    __shared__ float tile[64][65];
    int tid = threadIdx.x;
    int r0 = blockIdx.y * 64, c0 = blockIdx.x * 64;
    int lr = tid >> 4, lc = (tid & 15) * 4;
#pragma unroll
    for (int i = 0; i < 4; i++) {
        float4 v = *(const float4*)&src[(size_t)(r0 + i * 16 + lr) * src_cols + c0 + lc];
        tile[i * 16 + lr][lc] = v.x; tile[i * 16 + lr][lc + 1] = v.y;
        tile[i * 16 + lr][lc + 2] = v.z; tile[i * 16 + lr][lc + 3] = v.w;
    }
    __syncthreads();
#pragma unroll
    for (int i = 0; i < 4; i++) {
        int cc = i * 16 + lr;
        int rr = (tid & 15) * 4;
        bf16x4 o;
#pragma unroll
        for (int j = 0; j < 4; j++) o[j] = (__bf16)tile[rr + j][cc];
        *(bf16x4*)&dst[(size_t)(c0 + cc) * src_rows + r0 + rr] = o;
    }
}

// ---------------- repack per-head qkv weights -> transposed bf16 [2304][768]
__global__ __launch_bounds__(256) void repack_qkv_t_kernel(
    const float* __restrict__ Wq, const float* __restrict__ Wk, const float* __restrict__ Wv,
    const float* __restrict__ bq, const float* __restrict__ bk, const float* __restrict__ bv,
    __bf16* __restrict__ Wt, float* __restrict__ bp) {
    __shared__ float tile[64][65];
    int tid = threadIdx.x;
    int which = blockIdx.y / 12, h = blockIdx.y - which * 12;
    int d0 = blockIdx.x * 64;
    const float* W = (which == 0) ? Wq : ((which == 1) ? Wk : Wv);
    const float* src = W + ((size_t)h * D_EMB + d0) * HEAD;
    int lr = tid >> 4, lc = (tid & 15) * 4;
#pragma unroll
    for (int i = 0; i < 4; i++) {
        float4 v = *(const float4*)&src[(size_t)(i * 16 + lr) * HEAD + lc];
        tile[i * 16 + lr][lc] = v.x; tile[i * 16 + lr][lc + 1] = v.y;
        tile[i * 16 + lr][lc + 2] = v.z; tile[i * 16 + lr][lc + 3] = v.w;
    }
    __syncthreads();
#pragma unroll
    for (int i = 0; i < 4; i++) {
        int e = i * 16 + lr;
        int dd = (tid & 15) * 4;
        bf16x4 o;
#pragma unroll
        for (int j = 0; j < 4; j++) o[j] = (__bf16)tile[dd + j][e];
        *(bf16x4*)&Wt[(size_t)(which * 768 + h * 64 + e) * D_EMB + d0 + dd] = o;
    }
    if (blockIdx.x == 0 && tid < 64) {
        const float* bb = (which == 0) ? bq : ((which == 1) ? bk : bv);
        bp[which * 768 + h * 64 + tid] = bb[h * 64 + tid];
    }
}

// ---------------- layernorm over 768, bf16 output ----------------
__global__ __launch_bounds__(256) void ln_kernel(const float* __restrict__ x,
                                                 const float* __restrict__ lw,
                                                 const float* __restrict__ lb,
                                                 __bf16* __restrict__ y) {
    int row = blockIdx.x;
    int tid = threadIdx.x;
    const float* xr = x + (size_t)row * D_EMB;
    float a0 = xr[tid], a1 = xr[tid + 256], a2 = xr[tid + 512];
    float s = a0 + a1 + a2;
    float ss = a0 * a0 + a1 * a1 + a2 * a2;
#pragma unroll
    for (int off = 32; off > 0; off >>= 1) {
        s += __shfl_down(s, off, 64);
        ss += __shfl_down(ss, off, 64);
    }
    __shared__ float red[8];
    __shared__ float stats[2];
    int wv = tid >> 6, lane = tid & 63;
    if (lane == 0) { red[wv] = s; red[4 + wv] = ss; }
    __syncthreads();
    if (tid == 0) {
        float S = red[0] + red[1] + red[2] + red[3];
        float SS = red[4] + red[5] + red[6] + red[7];
        float mu = S * (1.0f / D_EMB);
        float var = SS * (1.0f / D_EMB) - mu * mu;
        stats[0] = mu;
        stats[1] = rsqrtf(var + 1e-5f);
    }
    __syncthreads();
    float mu = stats[0], rs = stats[1];
    __bf16* yr = y + (size_t)row * D_EMB;
    yr[tid]       = (__bf16)((a0 - mu) * rs * lw[tid]       + lb[tid]);
    yr[tid + 256] = (__bf16)((a1 - mu) * rs * lw[tid + 256] + lb[tid + 256]);
    yr[tid + 512] = (__bf16)((a2 - mu) * rs * lw[tid + 512] + lb[tid + 512]);
}

// ---------------- bf16 MFMA GEMM (B^T layout), swapped operands -------------
// acc = mfma(B,A) holds C^T fragments: lane owns row (m)=...+c and 4
// consecutive cols (n)=...+quad*4+{0..3}. Epilogue routing (all bf16):
//   col in [vcol0, N)   : V^T[e][tok] (tok-granule XOR swizzle), 4 scalar
//   col in [kcol0,kcol1): K' granule-XOR swizzle, bf16x4
//   else                : bf16x4 at Cb + kz*PART_STRIDE
__global__ __launch_bounds__(256) void mfma_gemm_bt(
    const __bf16* __restrict__ A, int lda,
    const __bf16* __restrict__ Bt, int ldb,
    const float* __restrict__ bias,
    __bf16* __restrict__ Cb, int ldc,
    int Kc, int act, int qlimit,
    __bf16* __restrict__ VTout, int vtok, int vcol0, int kcol0, int kcol1) {
    __shared__ __bf16 As[128 * 32];
    __shared__ __bf16 Bs[128 * 32];
    int tid = threadIdx.x;
    int bx = blockIdx.x, by = blockIdx.y, kz = blockIdx.z;
    int w = tid >> 6, lane = tid & 63;
    int c = lane & 15, quad = lane >> 4;
    int wm = (w >> 1) * 64, wn = (w & 1) * 64;

    f32x4 acc[4][4];
#pragma unroll
    for (int i = 0; i < 4; i++)
#pragma unroll
        for (int j = 0; j < 4; j++) acc[i][j] = (f32x4){0.f, 0.f, 0.f, 0.f};

    int srow = tid >> 2;
    int scol = (tid & 3) * 8;
    const __bf16* Ag = A + (size_t)(by * 128 + srow) * lda + (size_t)kz * Kc + scol;
    const __bf16* Bg = Bt + (size_t)(bx * 128 + srow) * ldb + (size_t)kz * Kc + scol;
    char* AsB = (char*)As + w * 1024;
    char* BsB = (char*)Bs + w * 1024;

    for (int k0 = 0; k0 < Kc; k0 += 32) {
        gld16(Ag + k0, AsB);
        gld16(Ag + (size_t)64 * lda + k0, AsB + 4096);
        gld16(Bg + k0, BsB);
        gld16(Bg + (size_t)64 * ldb + k0, BsB + 4096);
        __syncthreads();
        bf16x8 af[4], bfr[4];
#pragma unroll
        for (int mi = 0; mi < 4; mi++)
            af[mi] = *(const bf16x8*)&As[(wm + mi * 16 + c) * 32 + quad * 8];
#pragma unroll
        for (int ni = 0; ni < 4; ni++)
            bfr[ni] = *(const bf16x8*)&Bs[(wn + ni * 16 + c) * 32 + quad * 8];
#pragma unroll
        for (int mi = 0; mi < 4; mi++)
#pragma unroll
            for (int ni = 0; ni < 4; ni++)
                acc[mi][ni] = __builtin_amdgcn_mfma_f32_16x16x32_bf16(
                    bfr[ni], af[mi], acc[mi][ni], 0, 0, 0);   // swapped: C^T frags
        __syncthreads();
    }

#pragma unroll
    for (int mi = 0; mi < 4; mi++) {
#pragma unroll
        for (int ni = 0; ni < 4; ni++) {
            int row = by * 128 + wm + mi * 16 + c;                 // C row
            int colbase = bx * 128 + wn + ni * 16 + quad * 4;      // 4 consecutive C cols
            float bvv[4] = {0.f, 0.f, 0.f, 0.f};
            if (bias && kz == 0) {
                float4 b4 = *(const float4*)&bias[colbase];
                bvv[0] = b4.x; bvv[1] = b4.y; bvv[2] = b4.z; bvv[3] = b4.w;
            }
            float qs = (colbase < qlimit) ? 0.125f : 1.0f;   // qlimit%4==0 -> uniform
            float v[4];
#pragma unroll
            for (int r = 0; r < 4; r++) {
                float t = (acc[mi][ni][r] + bvv[r]) * qs;
                if (act == 1) t = t / (1.0f + __expf(-t));
                v[r] = t;
            }
            if (VTout && colbase >= vcol0) {
                int hc = colbase - vcol0;
                int hh = hc >> 6, ebase = hc & 63;
                int tok = row;
#pragma unroll
                for (int r = 0; r < 4; r++) {
                    int e = ebase + r;
                    int sl = ((((tok >> 3) & 7) ^ (e & 7)) << 3) | (tok & 7);
                    VTout[(size_t)(hh * 64 + e) * vtok + (tok & ~63) + sl] = (__bf16)v[r];
                }
            } else if (colbase >= kcol0 && colbase < kcol1) {
                int hc = colbase - kcol0;
                int hh = hc >> 6, ebase = hc & 63;
                int tok = row;
                int es = (((ebase >> 3) ^ (tok & 7)) << 3) | (ebase & 7);
                bf16x4 pv;
#pragma unroll
                for (int r = 0; r < 4; r++) pv[r] = (__bf16)v[r];
                *(bf16x4*)&Cb[(size_t)tok * ldc + kcol0 + hh * 64 + es] = pv;
            } else {
                __bf16* dst = Cb + (size_t)kz * PART_STRIDE;
                bf16x4 pv;
#pragma unroll
                for (int r = 0; r < 4; r++) pv[r] = (__bf16)v[r];
                *(bf16x4*)&dst[(size_t)row * ldc + colbase] = pv;
            }
        }
    }
}

// ---------------- flash MFMA attention, 128 q/block, swizzled K/V -----------
// Q [8192][qld] bf16 (pre-scaled), K' [tok][kld] swizzled per-head at h*64,
// VTg [12*64][vtok] per-head V^T, tok-granule XOR swizzled (no pi).
// S computed with swapped operands -> lane holds 4 consecutive kv -> b64 P write.
__global__ __launch_bounds__(128, 2) void mfma_attn(
    const __bf16* __restrict__ Q, int qld,
    const __bf16* __restrict__ Kp, int kld,
    const __bf16* __restrict__ VTg, int vtok,
    int kv_tokens, float* __restrict__ X) {
    __shared__ __bf16 Kt[64 * 64];     // [s][d] swizzled granules
    __shared__ __bf16 VT[80 * 64];     // [e][s] swizzled; rows 64..79 ones/zeros
    __shared__ __bf16 Ps[128 * 76];    // [q][s] stride 76; also Q staging (stride 64)
    int tid = threadIdx.x;
    int qt = blockIdx.x & 7;
    int bh = blockIdx.x >> 3;
    int b = bh / N_HEADS, h = bh - b * N_HEADS;
    int w = tid >> 6, lane = tid & 63, c = lane & 15, quad = lane >> 4;
    int q0 = qt * 128;

    // ones/zeros tail rows of VT
    for (int i = tid; i < 16 * 64; i += 128)
        VT[64 * 64 + i] = (i < 64) ? (__bf16)1.0f : (__bf16)0.0f;

    // stage Q (128x64) into Ps area, stride 64
    {
        const __bf16* Qg = Q + (size_t)(b * T_IMG + q0 + (tid >> 3)) * qld
                           + h * HEAD + (tid & 7) * 8;
        char* QsB = (char*)Ps + w * 1024;
#pragma unroll
        for (int j = 0; j < 8; j++)
            gld16(Qg + (size_t)j * 16 * qld, QsB + j * 2048);
    }
    __syncthreads();
    bf16x8 qa[4][2];
#pragma unroll
    for (int st = 0; st < 4; st++)
#pragma unroll
        for (int ch = 0; ch < 2; ch++)
            qa[st][ch] = *(const bf16x8*)&Ps[(w * 64 + st * 16 + c) * 64 + ch * 32 + quad * 8];
    __syncthreads();

    f32x4 o[4][5];
#pragma unroll
    for (int st = 0; st < 4; st++)
#pragma unroll
        for (int ut = 0; ut < 5; ut++) o[st][ut] = (f32x4){0.f, 0.f, 0.f, 0.f};

    char* KtB = (char*)Kt + w * 1024;
    char* VtB = (char*)VT + w * 1024;
    int ntiles = kv_tokens >> 6;
    for (int t = 0; t < ntiles; t++) {
        const __bf16* Kg = Kp + (size_t)(b * kv_tokens + t * 64 + (tid >> 3)) * kld
                           + h * HEAD + (tid & 7) * 8;
        const __bf16* Vg = VTg + (size_t)(h * HEAD + (tid >> 3)) * vtok
                           + b * kv_tokens + t * 64 + (tid & 7) * 8;
#pragma unroll
        for (int j = 0; j < 4; j++) {
            gld16(Kg + (size_t)j * 16 * kld, KtB + j * 2048);
            gld16(Vg + (size_t)j * 16 * vtok, VtB + j * 2048);
        }
        __syncthreads();   // (1) K/V tiles visible

        // ---- S^T = K Q^T (swapped): lane holds kv=nt*16+quad*4+r, q=st*16+c
        bf16x8 kb[4][2];
#pragma unroll
        for (int nt = 0; nt < 4; nt++)
#pragma unroll
            for (int ch = 0; ch < 2; ch++)
                kb[nt][ch] = *(const bf16x8*)&Kt[(nt * 16 + c) * 64
                                + (((ch * 4 + quad) ^ (c & 7)) << 3)];
#pragma unroll
        for (int st = 0; st < 4; st++) {
            f32x4 s[4];
#pragma unroll
            for (int nt = 0; nt < 4; nt++) {
                s[nt] = (f32x4){0.f, 0.f, 0.f, 0.f};
                s[nt] = __builtin_amdgcn_mfma_f32_16x16x32_bf16(kb[nt][0], qa[st][0], s[nt], 0, 0, 0);
                s[nt] = __builtin_amdgcn_mfma_f32_16x16x32_bf16(kb[nt][1], qa[st][1], s[nt], 0, 0, 0);
            }
            // P write: 4 consecutive kv per (nt) -> bf16x4
#pragma unroll
            for (int nt = 0; nt < 4; nt++) {
                bf16x4 pk;
#pragma unroll
                for (int r = 0; r < 4; r++) pk[r] = (__bf16)__expf(s[nt][r]);
                *(bf16x4*)&Ps[(size_t)(w * 64 + st * 16 + c) * 76 + nt * 16 + quad * 4] = pk;
            }
        }
        __syncthreads();   // (2) P visible

        // ---- O += P V ; ut=4 = ones row (l)
        bf16x8 vb[5][2];
#pragma unroll
        for (int ut = 0; ut < 5; ut++)
#pragma unroll
            for (int ch = 0; ch < 2; ch++)
                vb[ut][ch] = *(const bf16x8*)&VT[(ut * 16 + c) * 64
                                + (((ch * 4 + quad) ^ (c & 7)) << 3)];
#pragma unroll
        for (int st = 0; st < 4; st++) {
            bf16x8 pa0 = *(const bf16x8*)&Ps[(w * 64 + st * 16 + c) * 76 + quad * 8];
            bf16x8 pa1 = *(const bf16x8*)&Ps[(w * 64 + st * 16 + c) * 76 + 32 + quad * 8];
#pragma unroll
            for (int ut = 0; ut < 5; ut++) {
                o[st][ut] = __builtin_amdgcn_mfma_f32_16x16x32_bf16(pa0, vb[ut][0], o[st][ut], 0, 0, 0);
                o[st][ut] = __builtin_amdgcn_mfma_f32_16x16x32_bf16(pa1, vb[ut][1], o[st][ut], 0, 0, 0);
            }
        }
        __syncthreads();   // (3) safe to restage K/V/P
    }

    // ---- epilogue: l = o[st][4] at c==0 lanes; X += O / l
#pragma unroll
    for (int st = 0; st < 4; st++) {
        float lr[4];
#pragma unroll
        for (int r = 0; r < 4; r++) lr[r] = __shfl(o[st][4][r], lane & 48, 64);
#pragma unroll
        for (int ut = 0; ut < 4; ut++) {
#pragma unroll
            for (int r = 0; r < 4; r++) {
                int row = b * T_IMG + q0 + w * 64 + st * 16 + quad * 4 + r;
                int col = h * HEAD + ut * 16 + c;
                X[(size_t)row * D_EMB + col] += o[st][ut][r] / lr[r];
            }
        }
    }
}

// ---------------------------------------------------------------------------
extern "C" void kernel_launch(void* const* d_in, const int* in_sizes, int n_in,
                              void* d_out, int out_size, void* d_ws, size_t ws_size,
                              hipStream_t stream) {
    const float* img  = (const float*)d_in[0];
    const float* ctx  = (const float*)d_in[1];
    const float* ln1w = (const float*)d_in[2];  const float* ln1b = (const float*)d_in[3];
    const float* sWq  = (const float*)d_in[4];  const float* sbq  = (const float*)d_in[5];
    const float* sWk  = (const float*)d_in[6];  const float* sbk  = (const float*)d_in[7];
    const float* sWv  = (const float*)d_in[8];  const float* sbv  = (const float*)d_in[9];
    const float* ln2w = (const float*)d_in[10]; const float* ln2b = (const float*)d_in[11];
    const float* cWq  = (const float*)d_in[12]; const float* cbq  = (const float*)d_in[13];
    const float* cWk  = (const float*)d_in[14]; const float* cbk  = (const float*)d_in[15];
    const float* cWv  = (const float*)d_in[16]; const float* cbv  = (const float*)d_in[17];
    const float* ln3w = (const float*)d_in[18]; const float* ln3b = (const float*)d_in[19];
    const float* W1   = (const float*)d_in[20]; const float* b1   = (const float*)d_in[21];
    const float* W2   = (const float*)d_in[22]; const float* b2   = (const float*)d_in[23];

    float* X = (float*)d_out;

    // workspace layout. LNb+VTg adjacent = W2 split-K partial overlay.
    char* p = (char*)d_ws;
    __bf16* LNb  = (__bf16*)p; p += (size_t)ROWS_IMG * D_EMB * 2;       // 12.6 MB
    __bf16* VTg  = (__bf16*)p; p += (size_t)12 * 64 * ROWS_IMG * 2;     // 12.6 MB
    __bf16* BIG  = (__bf16*)p; p += (size_t)ROWS_IMG * FF_DIM * 2;      // 50.3 MB
    __bf16* ctxb = (__bf16*)p; p += (size_t)ROWS_CTX * D_EMB * 2;       // 3.1 MB
    __bf16* Wt   = (__bf16*)p; p += (size_t)2304 * 768 * 2;             // 3.5 MB
    __bf16* cWt  = (__bf16*)p; p += (size_t)2304 * 768 * 2;             // 3.5 MB
    __bf16* W1t  = (__bf16*)p; p += (size_t)FF_DIM * 768 * 2;           // 4.7 MB
    __bf16* W2t  = (__bf16*)p; p += (size_t)768 * FF_DIM * 2;           // 4.7 MB
    __bf16* VTc  = (__bf16*)p; p += (size_t)12 * 64 * ROWS_CTX * 2;     // 3.1 MB
    float*  bp   = (float*)p;  p += 2304 * 4;
    float*  cbp  = (float*)p;  p += 2304 * 4;
    __bf16* Pk   = LNb;   // split-K partials overlay
    __bf16* QKVb = BIG;
    __bf16* Qc   = BIG;
    __bf16* KVc  = BIG + (size_t)ROWS_IMG * 768;
    __bf16* FFh  = BIG;

    // ---- x = img; weight preprocessing ----
    copy4_kernel<<<ROWS_IMG * D_EMB / 4 / 256, 256, 0, stream>>>(
        (const float4*)img, (float4*)X);
    cvt_bf16_kernel<<<(ROWS_CTX * D_EMB / 4 + 255) / 256, 256, 0, stream>>>(
        ctx, ctxb, ROWS_CTX * D_EMB / 4);
    repack_qkv_t_kernel<<<dim3(12, 36), 256, 0, stream>>>(
        sWq, sWk, sWv, sbq, sbk, sbv, Wt, bp);
    repack_qkv_t_kernel<<<dim3(12, 36), 256, 0, stream>>>(
        cWq, cWk, cWv, cbq, cbk, cbv, cWt, cbp);
    transpose_cvt_kernel<<<dim3(FF_DIM / 64, 768 / 64), 256, 0, stream>>>(
        W1, W1t, 768, FF_DIM);
    transpose_cvt_kernel<<<dim3(768 / 64, FF_DIM / 64), 256, 0, stream>>>(
        W2, W2t, FF_DIM, 768);

    // ---- stage 1: self attention ----
    ln_kernel<<<ROWS_IMG, 256, 0, stream>>>(X, ln1w, ln1b, LNb);
    mfma_gemm_bt<<<dim3(2304 / 128, ROWS_IMG / 128), 256, 0, stream>>>(
        LNb, D_EMB, Wt, D_EMB, bp, QKVb, 2304, D_EMB, 0, 768,
        VTg, ROWS_IMG, 1536, 768, 1536);
    mfma_attn<<<96 * 8, 128, 0, stream>>>(
        QKVb, 2304, QKVb + 768, 2304, VTg, ROWS_IMG, T_IMG, X);

    // ---- stage 2: cross attention ----
    ln_kernel<<<ROWS_IMG, 256, 0, stream>>>(X, ln2w, ln2b, LNb);
    mfma_gemm_bt<<<dim3(768 / 128, ROWS_IMG / 128), 256, 0, stream>>>(
        LNb, D_EMB, cWt, D_EMB, cbp, Qc, 768, D_EMB, 0, 768,
        nullptr, 0, BIGCOL, BIGCOL, BIGCOL);
    mfma_gemm_bt<<<dim3(1536 / 128, ROWS_CTX / 128), 256, 0, stream>>>(
        ctxb, D_EMB, cWt + (size_t)768 * 768, D_EMB, cbp + 768,
        KVc, 1536, D_EMB, 0, 0,
        VTc, ROWS_CTX, 768, 0, 768);
    mfma_attn<<<96 * 8, 128, 0, stream>>>(
        Qc, 768, KVc, 1536, VTc, ROWS_CTX, T_CTX, X);

    // ---- stage 3: MLP ----
    ln_kernel<<<ROWS_IMG, 256, 0, stream>>>(X, ln3w, ln3b, LNb);
    mfma_gemm_bt<<<dim3(FF_DIM / 128, ROWS_IMG / 128), 256, 0, stream>>>(
        LNb, D_EMB, W1t, D_EMB, b1, FFh, FF_DIM, D_EMB, 1, 0,
        nullptr, 0, BIGCOL, BIGCOL, BIGCOL);
    mfma_gemm_bt<<<dim3(768 / 128, ROWS_IMG / 128, 2), 256, 0, stream>>>(
        FFh, FF_DIM, W2t, FF_DIM, nullptr, Pk, D_EMB, 1536, 0, 0,
        nullptr, 0, BIGCOL, BIGCOL, BIGCOL);
    reduce_w2_kernel<<<ROWS_IMG * D_EMB / 4 / 256, 256, 0, stream>>>(Pk, b2, X);
}